// Round 1
// baseline (95.918 us; speedup 1.0000x reference)
//
#include <hip/hip_runtime.h>
#include <math.h>

#define NPTS 1024
#define CH 256
#define CW 256

// -------- prep: fold all per-point constants into a packed table in d_ws ----
// A[n] = (t00, t10, b0, t01)   where tij = 0.5 * (matrix_offsets + s*I)[i][j]
// B[n] = (t11, b1, ca0, ca1)   b_j = -(ly*t0j + lx*t1j),  ca_c = color_c*alpha
// C[n] = ca2
__global__ __launch_bounds__(256) void prep_kernel(
    const float* __restrict__ loc,   // (N,2)  [y, x]
    const float* __restrict__ mo,    // (N,2,2)
    const float* __restrict__ mso,   // (N,)
    const float* __restrict__ col,   // (N,3)
    const float* __restrict__ alp,   // (N,)
    float4* __restrict__ A,
    float4* __restrict__ B,
    float*  __restrict__ C)
{
    int n = blockIdx.x * blockDim.x + threadIdx.x;
    if (n >= NPTS) return;
    float s   = 16.0f * __expf(mso[n]);   // sqrt(1024)/2 * exp(offset)
    float t00 = 0.5f * (mo[4*n+0] + s);
    float t01 = 0.5f * (mo[4*n+1]);
    float t10 = 0.5f * (mo[4*n+2]);
    float t11 = 0.5f * (mo[4*n+3] + s);
    float ly  = loc[2*n+0];
    float lx  = loc[2*n+1];
    float b0  = -(ly*t00 + lx*t10);
    float b1  = -(ly*t01 + lx*t11);
    float a   = alp[n];
    A[n] = make_float4(t00, t10, b0, t01);
    B[n] = make_float4(t11, b1, col[3*n+0]*a, col[3*n+1]*a);
    C[n] = col[3*n+2]*a;
}

// -------- render: 1 pixel per thread, loop over all points ------------------
__global__ __launch_bounds__(256) void render_kernel(
    const float4* __restrict__ A,
    const float4* __restrict__ B,
    const float*  __restrict__ C,
    float* __restrict__ out)
{
    int tid = blockIdx.x * 256 + threadIdx.x;
    int h = tid >> 8;          // W == 256
    int w = tid & 255;
    float y = fmaf((float)h, 2.0f/255.0f, -1.0f);
    float x = fmaf((float)w, 2.0f/255.0f, -1.0f);

    float acc0 = 0.0f, acc1 = 0.0f, acc2 = 0.0f;

    #pragma unroll 8
    for (int n = 0; n < NPTS; ++n) {
        float4 a = A[n];   // uniform index -> scalar loads expected
        float4 b = B[n];
        float  c = C[n];
        float t0 = fmaf(y, a.x, fmaf(x, a.y, a.z));
        float t1 = fmaf(y, a.w, fmaf(x, b.x, b.y));
        float m  = 1.0f - (fabsf(t0) + fabsf(t1));
        m = fmaxf(m, 0.0f);
        acc0 = fmaf(b.z, m, acc0);
        acc1 = fmaf(b.w, m, acc1);
        acc2 = fmaf(c,   m, acc2);
    }

    int o = tid * 3;
    out[o+0] = 1.0f / (1.0f + __expf(-4.0f * acc0));
    out[o+1] = 1.0f / (1.0f + __expf(-4.0f * acc1));
    out[o+2] = 1.0f / (1.0f + __expf(-4.0f * acc2));
}

extern "C" void kernel_launch(void* const* d_in, const int* in_sizes, int n_in,
                              void* d_out, int out_size, void* d_ws, size_t ws_size,
                              hipStream_t stream) {
    const float* loc = (const float*)d_in[0];   // locations      (1,1,N,2)
    const float* mo  = (const float*)d_in[1];   // matrix_offsets (N,2,2)
    const float* mso = (const float*)d_in[2];   // scale offsets  (N,1,1)
    const float* col = (const float*)d_in[3];   // colors         (1,1,N,3)
    const float* alp = (const float*)d_in[4];   // alphas         (1,1,N,1)
    float* out = (float*)d_out;

    float4* A = (float4*)d_ws;                  // 16 KB
    float4* B = A + NPTS;                       // 16 KB
    float*  C = (float*)(B + NPTS);             // 4 KB

    prep_kernel<<<(NPTS + 255) / 256, 256, 0, stream>>>(loc, mo, mso, col, alp, A, B, C);

    int pixels = CH * CW;
    render_kernel<<<pixels / 256, 256, 0, stream>>>(A, B, C, out);
}

// Round 2
// 95.850 us; speedup vs baseline: 1.0007x; 1.0007x over previous
//
#include <hip/hip_runtime.h>
#include <math.h>

#define NPTS 1024
#define CH 256
#define CW 256

// -------- prep: fold all per-point constants into a packed table in d_ws ----
// A[n] = (t00, t10, b0, t01)   where tij = 0.5 * (matrix_offsets + s*I)[i][j]
// B[n] = (t11, b1, ca0, ca1)   b_j = -(ly*t0j + lx*t1j),  ca_c = color_c*alpha
// C[n] = ca2
__global__ __launch_bounds__(256) void prep_kernel(
    const float* __restrict__ loc,   // (N,2)  [y, x]
    const float* __restrict__ mo,    // (N,2,2)
    const float* __restrict__ mso,   // (N,)
    const float* __restrict__ col,   // (N,3)
    const float* __restrict__ alp,   // (N,)
    float4* __restrict__ A,
    float4* __restrict__ B,
    float*  __restrict__ C)
{
    int n = blockIdx.x * blockDim.x + threadIdx.x;
    if (n >= NPTS) return;
    float s   = 16.0f * __expf(mso[n]);   // sqrt(1024)/2 * exp(offset)
    float t00 = 0.5f * (mo[4*n+0] + s);
    float t01 = 0.5f * (mo[4*n+1]);
    float t10 = 0.5f * (mo[4*n+2]);
    float t11 = 0.5f * (mo[4*n+3] + s);
    float ly  = loc[2*n+0];
    float lx  = loc[2*n+1];
    float b0  = -(ly*t00 + lx*t10);
    float b1  = -(ly*t01 + lx*t11);
    float a   = alp[n];
    A[n] = make_float4(t00, t10, b0, t01);
    B[n] = make_float4(t11, b1, col[3*n+0]*a, col[3*n+1]*a);
    C[n] = col[3*n+2]*a;
}

// -------- render: 1 pixel per thread, loop over all points ------------------
__global__ __launch_bounds__(256) void render_kernel(
    const float4* __restrict__ A,
    const float4* __restrict__ B,
    const float*  __restrict__ C,
    float* __restrict__ out)
{
    int tid = blockIdx.x * 256 + threadIdx.x;
    int h = tid >> 8;          // W == 256
    int w = tid & 255;
    float y = fmaf((float)h, 2.0f/255.0f, -1.0f);
    float x = fmaf((float)w, 2.0f/255.0f, -1.0f);

    float acc0 = 0.0f, acc1 = 0.0f, acc2 = 0.0f;

    #pragma unroll 8
    for (int n = 0; n < NPTS; ++n) {
        float4 a = A[n];   // uniform index -> scalar loads expected
        float4 b = B[n];
        float  c = C[n];
        float t0 = fmaf(y, a.x, fmaf(x, a.y, a.z));
        float t1 = fmaf(y, a.w, fmaf(x, b.x, b.y));
        float m  = 1.0f - (fabsf(t0) + fabsf(t1));
        m = fmaxf(m, 0.0f);
        acc0 = fmaf(b.z, m, acc0);
        acc1 = fmaf(b.w, m, acc1);
        acc2 = fmaf(c,   m, acc2);
    }

    int o = tid * 3;
    out[o+0] = 1.0f / (1.0f + __expf(-4.0f * acc0));
    out[o+1] = 1.0f / (1.0f + __expf(-4.0f * acc1));
    out[o+2] = 1.0f / (1.0f + __expf(-4.0f * acc2));
}

extern "C" void kernel_launch(void* const* d_in, const int* in_sizes, int n_in,
                              void* d_out, int out_size, void* d_ws, size_t ws_size,
                              hipStream_t stream) {
    const float* loc = (const float*)d_in[0];   // locations      (1,1,N,2)
    const float* mo  = (const float*)d_in[1];   // matrix_offsets (N,2,2)
    const float* mso = (const float*)d_in[2];   // scale offsets  (N,1,1)
    const float* col = (const float*)d_in[3];   // colors         (1,1,N,3)
    const float* alp = (const float*)d_in[4];   // alphas         (1,1,N,1)
    float* out = (float*)d_out;

    float4* A = (float4*)d_ws;                  // 16 KB
    float4* B = A + NPTS;                       // 16 KB
    float*  C = (float*)(B + NPTS);             // 4 KB

    prep_kernel<<<(NPTS + 255) / 256, 256, 0, stream>>>(loc, mo, mso, col, alp, A, B, C);

    int pixels = CH * CW;
    render_kernel<<<pixels / 256, 256, 0, stream>>>(A, B, C, out);
}